// Round 7
// baseline (183.358 us; speedup 1.0000x reference)
//
#include <hip/hip_runtime.h>
#include <hip/hip_bf16.h>

typedef unsigned short u16;
typedef __attribute__((ext_vector_type(8))) short bf16x8;
typedef __attribute__((ext_vector_type(4))) float f32x4;

#define N_MEM_C 65536
#define NNODES_C 50000
#define DDIM 128
#define LDA 136   // 272B rows: breaks power-of-2 bank aliasing
#define BM 128
#define NTHR 512
#define TIL(t) ((t) * 16384)

// bf16 [n][k] weight tiles (128x128 each):
// 0: msg_W1[0:128]^T (vi)   1: msg_W1[256:384]^T (vj)   2: msg_W2^T
// 3: hid_W1[0:128]^T (aggr) 4: hid_W1[128:256]^T (hidden)
// 5: (int_W @ hid_W1[256:384])^T    6: hid_W2^T
__device__ __align__(16) u16 g_WT[7 * 16384];
__device__ __align__(16) float g_relW[500 * 128];   // rel_table @ msg_W1[128:256]
__device__ __align__(16) float g_qsumM[64 * 128];   // qh@msg_W1[384:512] + qr@msg_W1[512:640]
__device__ __align__(16) float g_qsumH[64 * 128];   // same for hid_W1

__device__ __forceinline__ u16 f2bf_s(float f) {
  __hip_bfloat16 h = __float2bfloat16(f);
  u16 u; __builtin_memcpy(&u, &h, 2);
  return u;
}
__device__ __forceinline__ unsigned pk2(float a, float b) {
  __hip_bfloat162 h = __float22bfloat162_rn(make_float2(a, b));  // v_cvt_pk_bf16_f32
  unsigned u; __builtin_memcpy(&u, &h, 4);
  return u;
}
__device__ __forceinline__ float fast_tanh(float x) {
  float e = __expf(2.0f * x);
  return 1.0f - 2.0f / (e + 1.0f);   // inf-safe
}

// ---- prep kernels (unchanged) ----
extern "C" __global__ void prep_wt(const float* __restrict__ msg_W1,
                                   const float* __restrict__ msg_W2,
                                   const float* __restrict__ hid_W1,
                                   const float* __restrict__ hid_W2) {
  int i = blockIdx.x * 256 + threadIdx.x;
  int t = i >> 14, idx = i & 16383;
  int n = idx >> 7, k = idx & 127;
  const float* src; int dst;
  switch (t) {
    case 0:  src = msg_W1;             dst = TIL(0); break;
    case 1:  src = msg_W1 + 256 * 128; dst = TIL(1); break;
    case 2:  src = msg_W2;             dst = TIL(2); break;
    case 3:  src = hid_W1;             dst = TIL(3); break;
    case 4:  src = hid_W1 + 128 * 128; dst = TIL(4); break;
    default: src = hid_W2;             dst = TIL(6); break;
  }
  g_WT[dst + n * 128 + k] = f2bf_s(src[k * 128 + n]);
}

extern "C" __global__ void prep_weff(const float* __restrict__ hid_W1,
                                     const float* __restrict__ int_W) {
  int i = blockIdx.x * 256 + threadIdx.x;
  int n = i & 127, q = i >> 7;
  float s = 0.f;
  for (int p = 0; p < 128; ++p)
    s += int_W[q * 128 + p] * hid_W1[(256 + p) * 128 + n];
  g_WT[TIL(5) + n * 128 + q] = f2bf_s(s);
}

extern "C" __global__ void prep_relW(const float* __restrict__ rel_table,
                                     const float* __restrict__ msg_W1) {
  int i = blockIdx.x * 256 + threadIdx.x;
  if (i >= 500 * 128) return;
  int r = i >> 7, n = i & 127;
  float s = 0.f;
  for (int k = 0; k < 128; ++k)
    s += rel_table[r * 128 + k] * msg_W1[(128 + k) * 128 + n];
  g_relW[i] = s;
}

extern "C" __global__ void prep_qsum(const float* __restrict__ qh,
                                     const float* __restrict__ qr,
                                     const float* __restrict__ msg_W1,
                                     const float* __restrict__ hid_W1) {
  int i = blockIdx.x * 256 + threadIdx.x;
  int g = i >> 7, n = i & 127;
  float sM = 0.f, sH = 0.f;
  for (int k = 0; k < 128; ++k) {
    float h = qh[g * 128 + k], r = qr[g * 128 + k];
    sM += h * msg_W1[(384 + k) * 128 + n] + r * msg_W1[(512 + k) * 128 + n];
    sH += h * hid_W1[(384 + k) * 128 + n] + r * hid_W1[(512 + k) * 128 + n];
  }
  g_qsumM[i] = sM;
  g_qsumH[i] = sH;
}

// ---- staging, split into load (issue-early) and store (write-late) ----
// 1024 slots = 128 rows x 8 segs of 16 floats; 512 threads -> 2 slots each.
// MODE 0: idx from LDS array; MODE 1: idx = base + r
template <int MODE>
__device__ __forceinline__ void stage_load(float4 (&ld)[8], const float* __restrict__ src,
                                           const int* idxArr, int base, int tid) {
#pragma unroll
  for (int it = 0; it < 2; ++it) {
    int slot = it * NTHR + tid;
    int r = slot >> 3, seg = slot & 7;
    int idx = (MODE == 1) ? (base + r) : idxArr[r];
    const float4* p = (const float4*)(src + (size_t)idx * DDIM + seg * 16);
    ld[it * 4 + 0] = p[0]; ld[it * 4 + 1] = p[1];
    ld[it * 4 + 2] = p[2]; ld[it * 4 + 3] = p[3];
  }
}

// SCALED: multiply each row by scArr[r] before packing (for na * hidden_uncon)
template <int SCALED>
__device__ __forceinline__ void stage_store(u16 (*A)[LDA], float4 (&ld)[8],
                                            const float* scArr, int tid) {
#pragma unroll
  for (int it = 0; it < 2; ++it) {
    int slot = it * NTHR + tid;
    int r = slot >> 3, seg = slot & 7;
    float sc = SCALED ? scArr[r] : 1.0f;
    float4 f0 = ld[it * 4 + 0], f1 = ld[it * 4 + 1];
    float4 f2 = ld[it * 4 + 2], f3 = ld[it * 4 + 3];
    if (SCALED) {
      f0.x *= sc; f0.y *= sc; f0.z *= sc; f0.w *= sc;
      f1.x *= sc; f1.y *= sc; f1.z *= sc; f1.w *= sc;
      f2.x *= sc; f2.y *= sc; f2.z *= sc; f2.w *= sc;
      f3.x *= sc; f3.y *= sc; f3.z *= sc; f3.w *= sc;
    }
    uint4* q = (uint4*)&A[r][seg * 16];
    q[0] = make_uint4(pk2(f0.x, f0.y), pk2(f0.z, f0.w), pk2(f1.x, f1.y), pk2(f1.z, f1.w));
    q[1] = make_uint4(pk2(f2.x, f2.y), pk2(f2.z, f2.w), pk2(f3.x, f3.y), pk2(f3.z, f3.w));
  }
}

// A(128x128 LDS) @ WT(128x128 bf16 [n][k], from global/L2) -> acc[4][2]
// wave sub-tile: rows wr*64..+64, cols wc*32..+32
__device__ __forceinline__ void gemm128g(const u16 (*A)[LDA], const u16* __restrict__ WT,
                                         f32x4 (&acc)[4][2], int wr, int wc, int l16, int l4) {
  const u16* wb = WT + (wc * 32 + l16) * 128 + l4 * 8;
#pragma unroll
  for (int ks = 0; ks < 4; ++ks) {
    bf16x8 av[4], bv[2];
#pragma unroll
    for (int nr = 0; nr < 2; ++nr)
      bv[nr] = *(const bf16x8*)(wb + nr * 16 * 128 + ks * 32);
#pragma unroll
    for (int mr = 0; mr < 4; ++mr)
      av[mr] = *(const bf16x8*)&A[wr * 64 + mr * 16 + l16][ks * 32 + l4 * 8];
#pragma unroll
    for (int mr = 0; mr < 4; ++mr)
#pragma unroll
      for (int nr = 0; nr < 2; ++nr)
        acc[mr][nr] = __builtin_amdgcn_mfma_f32_16x16x32_bf16(av[mr], bv[nr], acc[mr][nr], 0, 0, 0);
  }
}

extern "C" __global__ __launch_bounds__(NTHR, 4) void fused_flow(
    const float* __restrict__ hidden, const int* __restrict__ seen_edges,
    const int* __restrict__ memorized, const float* __restrict__ node_att,
    const float* __restrict__ hidden_uncon,
    const float* __restrict__ msg_b1, const float* __restrict__ msg_b2,
    const float* __restrict__ hid_b1, const float* __restrict__ hid_b2,
    float* __restrict__ out) {
  __shared__ u16 sA[2][BM][LDA];      // double-buffered A tiles (69632 B)
  __shared__ int sEg[4][BM];
  __shared__ int sRel[4][BM];
  __shared__ int sVi[4][BM];
  __shared__ int sMeg[BM];
  __shared__ int sMvm[BM];
  __shared__ float sNA[BM];

  const int tid = threadIdx.x;
  const int lane = tid & 63, wid = tid >> 6;
  const int wr = wid >> 2, wc = wid & 3;     // 2 x 4 wave grid; 64x32 per wave
  const int l16 = lane & 15, l4 = lane >> 4;
  const int j0 = blockIdx.x * BM;

  float mb1v[2], mb2v[2], hb1v[2], hb2v[2];
#pragma unroll
  for (int nr = 0; nr < 2; ++nr) {
    int col = wc * 32 + nr * 16 + l16;
    mb1v[nr] = msg_b1[col]; mb2v[nr] = msg_b2[col];
    hb1v[nr] = hid_b1[col]; hb2v[nr] = hid_b2[col];
  }

  // ---- upfront: all indices + vj tile -> sA[0] ----
  {
    int t = tid >> 7, r = tid & 127;
    int e = j0 + r + t * N_MEM_C;
    const int4* se = (const int4*)seen_edges + (size_t)e * 2;
    int4 lo = se[0], hi = se[1];
    sEg[t][r] = min(max(lo.x, 0), 63);
    sRel[t][r] = min(max(lo.w, 0), 499);
    sVi[t][r] = min(max(hi.z, 0), N_MEM_C - 1);
  }
  if (tid < BM) {
    int2 mn = ((const int2*)memorized)[j0 + tid];
    int eg = min(max(mn.x, 0), 63);
    int vm = min(max(mn.y, 0), NNODES_C - 1);
    sMeg[tid] = eg; sMvm[tid] = vm;
    sNA[tid] = node_att[(size_t)eg * NNODES_C + vm];
  }
  float4 ld[8];
  stage_load<1>(ld, hidden, nullptr, j0, tid);      // vj rows
  stage_store<0>(sA[0], ld, nullptr, tid);
  __syncthreads();                                  // B0: indices + vj tile ready

  const f32x4 zero4 = {0.f, 0.f, 0.f, 0.f};
  f32x4 acc_vj[4][2], aggr[4][2];
#pragma unroll
  for (int a = 0; a < 4; ++a)
#pragma unroll
    for (int b = 0; b < 2; ++b) { acc_vj[a][b] = zero4; aggr[a][b] = zero4; }

  // A0 loads in flight under the vj gemm; store to sA[1] (free buffer)
  stage_load<0>(ld, hidden, sVi[0], 0, tid);
  gemm128g(sA[0], g_WT + TIL(1), acc_vj, wr, wc, l16, l4);
  stage_store<0>(sA[1], ld, nullptr, tid);
  __syncthreads();                                  // B_pre: A0 in sA[1]

  // ---- edge loop: cur = (t+1)&1 -> tiles alternate sA[1], sA[0], ... ----
#pragma unroll 1
  for (int t = 0; t < 4; ++t) {
    const int cur = (t + 1) & 1;
    f32x4 acc[4][2];
#pragma unroll
    for (int a = 0; a < 4; ++a)
#pragma unroll
      for (int b = 0; b < 2; ++b) acc[a][b] = acc_vj[a][b];
    gemm128g(sA[cur], g_WT + TIL(0), acc, wr, wc, l16, l4);

    // gather-add: rel + query contributions (f32 tables, L2-hot)
#pragma unroll
    for (int mr = 0; mr < 4; ++mr)
#pragma unroll
      for (int i = 0; i < 4; ++i) {
        int r = wr * 64 + mr * 16 + l4 * 4 + i;
        const float* pr = g_relW + sRel[t][r] * 128;
        const float* pq = g_qsumM + sEg[t][r] * 128;
#pragma unroll
        for (int nr = 0; nr < 2; ++nr) {
          int c = wc * 32 + nr * 16 + l16;
          acc[mr][nr][i] += pr[c] + pq[c];
        }
      }
    __syncthreads();                                // B1: readers of sA[cur] done

    // h_t -> sA[cur] (overwrite); stage A_{t+1} -> sA[cur^1]
#pragma unroll
    for (int mr = 0; mr < 4; ++mr)
#pragma unroll
      for (int nr = 0; nr < 2; ++nr)
#pragma unroll
        for (int i = 0; i < 4; ++i) {
          float v = acc[mr][nr][i] + mb1v[nr];
          v = (v >= 0.f) ? v : 0.2f * v;
          sA[cur][wr * 64 + mr * 16 + l4 * 4 + i][wc * 32 + nr * 16 + l16] = f2bf_s(v);
        }
    if (t < 3) {
      stage_load<0>(ld, hidden, sVi[t + 1], 0, tid);
      stage_store<0>(sA[cur ^ 1], ld, nullptr, tid);
    }
    __syncthreads();                                // B2: h + next A visible

    f32x4 acc2[4][2];
#pragma unroll
    for (int a = 0; a < 4; ++a)
#pragma unroll
      for (int b = 0; b < 2; ++b) acc2[a][b] = zero4;
    gemm128g(sA[cur], g_WT + TIL(2), acc2, wr, wc, l16, l4);
#pragma unroll
    for (int mr = 0; mr < 4; ++mr)
#pragma unroll
      for (int nr = 0; nr < 2; ++nr)
#pragma unroll
        for (int i = 0; i < 4; ++i)
          aggr[mr][nr][i] += fast_tanh(acc2[mr][nr][i] + mb2v[nr]);
    // next iteration's gemm1 reads sA[cur^1] (written before B2): no extra barrier
  }

  // ---- update phase. gemm2_3 just read sA[0]; sA[1] free since t=2 ----
  // chunk 0 tile: 0.5*aggr -> sA[1] (safe pre-barrier: sA[1] readers done at t=3 B1)
#pragma unroll
  for (int mr = 0; mr < 4; ++mr)
#pragma unroll
    for (int nr = 0; nr < 2; ++nr)
#pragma unroll
      for (int i = 0; i < 4; ++i)
        sA[1][wr * 64 + mr * 16 + l4 * 4 + i][wc * 32 + nr * 16 + l16] =
            f2bf_s(0.5f * aggr[mr][nr][i]);
  __syncthreads();                                  // B3: aggr tile ready, gemm2_3 done

  f32x4 accU[4][2];
#pragma unroll
  for (int a = 0; a < 4; ++a)
#pragma unroll
    for (int b = 0; b < 2; ++b) accU[a][b] = zero4;

  stage_load<1>(ld, hidden, nullptr, j0, tid);      // hidden[m] in flight
  gemm128g(sA[1], g_WT + TIL(3), accU, wr, wc, l16, l4);   // aggr chunk
  stage_store<0>(sA[0], ld, nullptr, tid);
  __syncthreads();                                  // B4

  stage_load<0>(ld, hidden_uncon, sMvm, 0, tid);    // uncon gathers in flight
  gemm128g(sA[0], g_WT + TIL(4), accU, wr, wc, l16, l4);   // hidden chunk
  stage_store<1>(sA[1], ld, sNA, tid);              // na * uncon -> sA[1]
  __syncthreads();                                  // B5

  gemm128g(sA[1], g_WT + TIL(5), accU, wr, wc, l16, l4);   // uncon @ Weff
#pragma unroll
  for (int mr = 0; mr < 4; ++mr)
#pragma unroll
    for (int i = 0; i < 4; ++i) {
      int r = wr * 64 + mr * 16 + l4 * 4 + i;
      const float* pq = g_qsumH + sMeg[r] * 128;
#pragma unroll
      for (int nr = 0; nr < 2; ++nr)
        accU[mr][nr][i] += pq[wc * 32 + nr * 16 + l16];
    }
  // h -> sA[0] (readers of sA[0] done via B5)
#pragma unroll
  for (int mr = 0; mr < 4; ++mr)
#pragma unroll
    for (int nr = 0; nr < 2; ++nr)
#pragma unroll
      for (int i = 0; i < 4; ++i) {
        float v = accU[mr][nr][i] + hb1v[nr];
        v = (v >= 0.f) ? v : 0.2f * v;
        sA[0][wr * 64 + mr * 16 + l4 * 4 + i][wc * 32 + nr * 16 + l16] = f2bf_s(v);
      }
  __syncthreads();                                  // B6

  f32x4 accF[4][2];
#pragma unroll
  for (int a = 0; a < 4; ++a)
#pragma unroll
    for (int b = 0; b < 2; ++b) accF[a][b] = zero4;
  gemm128g(sA[0], g_WT + TIL(6), accF, wr, wc, l16, l4);

#pragma unroll
  for (int mr = 0; mr < 4; ++mr)
#pragma unroll
    for (int nr = 0; nr < 2; ++nr)
#pragma unroll
      for (int i = 0; i < 4; ++i) {
        int row = j0 + wr * 64 + mr * 16 + l4 * 4 + i;
        int col = wc * 32 + nr * 16 + l16;
        size_t o = (size_t)row * DDIM + col;
        out[o] = hidden[o] + fast_tanh(accF[mr][nr][i] + hb2v[nr]);
      }
}

extern "C" void kernel_launch(void* const* d_in, const int* in_sizes, int n_in,
                              void* d_out, int out_size, void* d_ws, size_t ws_size,
                              hipStream_t stream) {
  (void)in_sizes; (void)n_in; (void)out_size; (void)d_ws; (void)ws_size;
  const float* hidden       = (const float*)d_in[0];
  const int*   seen_edges   = (const int*)d_in[1];
  const int*   memorized    = (const int*)d_in[2];
  const float* node_att     = (const float*)d_in[3];
  const float* hidden_uncon = (const float*)d_in[4];
  const float* qh           = (const float*)d_in[5];
  const float* qr           = (const float*)d_in[6];
  const float* rel_table    = (const float*)d_in[7];
  const float* msg_W1       = (const float*)d_in[8];
  const float* msg_b1       = (const float*)d_in[9];
  const float* msg_W2       = (const float*)d_in[10];
  const float* msg_b2       = (const float*)d_in[11];
  const float* hid_W1       = (const float*)d_in[12];
  const float* hid_b1       = (const float*)d_in[13];
  const float* hid_W2       = (const float*)d_in[14];
  const float* hid_b2       = (const float*)d_in[15];
  const float* int_W        = (const float*)d_in[16];

  prep_wt<<<dim3(6 * 16384 / 256), dim3(256), 0, stream>>>(msg_W1, msg_W2, hid_W1, hid_W2);
  prep_weff<<<dim3(64), dim3(256), 0, stream>>>(hid_W1, int_W);
  prep_relW<<<dim3(250), dim3(256), 0, stream>>>(rel_table, msg_W1);
  prep_qsum<<<dim3(32), dim3(256), 0, stream>>>(qh, qr, msg_W1, hid_W1);
  fused_flow<<<dim3(N_MEM_C / BM), dim3(NTHR), 0, stream>>>(
      hidden, seen_edges, memorized, node_att, hidden_uncon,
      msg_b1, msg_b2, hid_b1, hid_b2, (float*)d_out);
}

// Round 8
// 134.379 us; speedup vs baseline: 1.3645x; 1.3645x over previous
//
#include <hip/hip_runtime.h>
#include <hip/hip_bf16.h>

typedef unsigned short u16;
typedef __attribute__((ext_vector_type(8))) short bf16x8;
typedef __attribute__((ext_vector_type(4))) float f32x4;

#define N_MEM_C 65536
#define NNODES_C 50000
#define DDIM 128
#define BM 128
#define NTHR 512
#define TIL(t) ((t) * 16384)

// bf16 [n][k] weight tiles (128x128), stored PRE-SWIZZLED (XOR of 16B-granule
// index with row&7) so a linear global_load_lds yields the swizzled LDS image:
// 0: msg_W1[0:128]^T (vi)   1: msg_W1[256:384]^T (vj)   2: msg_W2^T
// 3: hid_W1[0:128]^T (aggr) 4: hid_W1[128:256]^T (hidden)
// 5: (int_W @ hid_W1[256:384])^T    6: hid_W2^T
__device__ __align__(16) u16 g_WT[7 * 16384];
__device__ __align__(16) float g_relW[500 * 128];   // rel_table @ msg_W1[128:256]
__device__ __align__(16) float g_qsumM[64 * 128];
__device__ __align__(16) float g_qsumH[64 * 128];
// bf16 copies of hidden / hidden_uncon (plain row-major, NOT swizzled;
// gathers apply the swizzle on the per-lane global address)
__device__ __align__(16) u16 g_hb[(size_t)N_MEM_C * DDIM];
__device__ __align__(16) u16 g_ub[(size_t)NNODES_C * DDIM];

#define SBAR() do { asm volatile("" ::: "memory"); __builtin_amdgcn_s_barrier(); \
                    asm volatile("" ::: "memory"); } while (0)
#define WAIT_VM0() asm volatile("s_waitcnt vmcnt(0)" ::: "memory")
#define WAIT_VM4() asm volatile("s_waitcnt vmcnt(4)" ::: "memory")
#define WAIT_LG0() asm volatile("s_waitcnt lgkmcnt(0)" ::: "memory")

__device__ __forceinline__ u16 f2bf_s(float f) {
  __hip_bfloat16 h = __float2bfloat16(f);
  u16 u; __builtin_memcpy(&u, &h, 2);
  return u;
}
__device__ __forceinline__ unsigned pk2(float a, float b) {
  __hip_bfloat162 h = __float22bfloat162_rn(make_float2(a, b));
  unsigned u; __builtin_memcpy(&u, &h, 4);
  return u;
}
__device__ __forceinline__ float bf2f(u16 u) {
  unsigned v = ((unsigned)u) << 16;
  float f; __builtin_memcpy(&f, &v, 4);
  return f;
}
__device__ __forceinline__ float fast_tanh(float x) {
  float e = __expf(2.0f * x);
  return 1.0f - 2.0f / (e + 1.0f);
}
// swizzled u16 offset within a [128][128] tile for logical (row r, col c)
__device__ __forceinline__ int swz_off(int r, int c) {
  return r * 128 + ((((c >> 3) ^ (r & 7)) << 3) | (c & 7));
}

// ---- prep: f32 -> bf16 copies of hidden & hidden_uncon ----
extern "C" __global__ void prep_conv(const float* __restrict__ hidden,
                                     const float* __restrict__ uncon) {
  const size_t NH = (size_t)N_MEM_C * DDIM / 8;   // 1048576 octets
  const size_t NU = (size_t)NNODES_C * DDIM / 8;  // 800000 octets
  size_t i = (size_t)blockIdx.x * 256 + threadIdx.x;
  const float* src; u16* dst; size_t o;
  if (i < NH) { src = hidden; dst = g_hb; o = i; }
  else if (i < NH + NU) { src = uncon; dst = g_ub; o = i - NH; }
  else return;
  const float4* p = (const float4*)(src + o * 8);
  float4 a = p[0], b = p[1];
  uint4 v = make_uint4(pk2(a.x, a.y), pk2(a.z, a.w), pk2(b.x, b.y), pk2(b.z, b.w));
  *(uint4*)(dst + o * 8) = v;
}

// ---- prep: transpose+convert+swizzle weight tiles ----
extern "C" __global__ void prep_wt(const float* __restrict__ msg_W1,
                                   const float* __restrict__ msg_W2,
                                   const float* __restrict__ hid_W1,
                                   const float* __restrict__ hid_W2) {
  int i = blockIdx.x * 256 + threadIdx.x;   // 6*16384 threads
  int t = i >> 14, idx = i & 16383;
  int n = idx >> 7, k = idx & 127;          // logical (row n, col k) of W^T
  const float* src; int dst;
  switch (t) {
    case 0:  src = msg_W1;             dst = TIL(0); break;
    case 1:  src = msg_W1 + 256 * 128; dst = TIL(1); break;
    case 2:  src = msg_W2;             dst = TIL(2); break;
    case 3:  src = hid_W1;             dst = TIL(3); break;
    case 4:  src = hid_W1 + 128 * 128; dst = TIL(4); break;
    default: src = hid_W2;             dst = TIL(6); break;
  }
  g_WT[dst + swz_off(n, k)] = f2bf_s(src[k * 128 + n]);
}

extern "C" __global__ void prep_weff(const float* __restrict__ hid_W1,
                                     const float* __restrict__ int_W) {
  int i = blockIdx.x * 256 + threadIdx.x;
  int n = i & 127, q = i >> 7;
  float s = 0.f;
  for (int p = 0; p < 128; ++p)
    s += int_W[q * 128 + p] * hid_W1[(256 + p) * 128 + n];
  g_WT[TIL(5) + swz_off(n, q)] = f2bf_s(s);
}

extern "C" __global__ void prep_relW(const float* __restrict__ rel_table,
                                     const float* __restrict__ msg_W1) {
  int i = blockIdx.x * 256 + threadIdx.x;
  if (i >= 500 * 128) return;
  int r = i >> 7, n = i & 127;
  float s = 0.f;
  for (int k = 0; k < 128; ++k)
    s += rel_table[r * 128 + k] * msg_W1[(128 + k) * 128 + n];
  g_relW[i] = s;
}

extern "C" __global__ void prep_qsum(const float* __restrict__ qh,
                                     const float* __restrict__ qr,
                                     const float* __restrict__ msg_W1,
                                     const float* __restrict__ hid_W1) {
  int i = blockIdx.x * 256 + threadIdx.x;
  int g = i >> 7, n = i & 127;
  float sM = 0.f, sH = 0.f;
  for (int k = 0; k < 128; ++k) {
    float h = qh[g * 128 + k], r = qr[g * 128 + k];
    sM += h * msg_W1[(384 + k) * 128 + n] + r * msg_W1[(512 + k) * 128 + n];
    sH += h * hid_W1[(384 + k) * 128 + n] + r * hid_W1[(512 + k) * 128 + n];
  }
  g_qsumM[i] = sM;
  g_qsumH[i] = sH;
}

// ---- async staging via global_load_lds (4 issues/wave, 16 rows/wave) ----
// rows: gather bf16 rows (idxArr==nullptr -> idx = base+r), swizzled source col
__device__ __forceinline__ void gload_rows(u16* lds_tile, const u16* __restrict__ gsrc,
                                           const int* idxArr, int base,
                                           int wid, int lane) {
  int rsub = lane >> 4, s = lane & 15;
#pragma unroll
  for (int k = 0; k < 4; ++k) {
    int r = wid * 16 + k * 4 + rsub;
    int idx = idxArr ? idxArr[r] : (base + r);
    const u16* gp = gsrc + (size_t)idx * DDIM + ((s ^ (r & 7)) << 3);
    u16* lp = lds_tile + (wid * 16 + k * 4) * 128;   // wave-uniform base
    __builtin_amdgcn_global_load_lds((const __attribute__((address_space(1))) void*)gp,
                                     (__attribute__((address_space(3))) void*)lp,
                                     16, 0, 0);
  }
}
// linear 32KB copy (pre-swizzled weight tile)
__device__ __forceinline__ void gload_lin(u16* lds_tile, const u16* __restrict__ gsrc,
                                          int wid, int lane) {
#pragma unroll
  for (int k = 0; k < 4; ++k) {
    int off = (wid * 4 + k) * 512;
    const u16* gp = gsrc + off + lane * 8;
    u16* lp = lds_tile + off;
    __builtin_amdgcn_global_load_lds((const __attribute__((address_space(1))) void*)gp,
                                     (__attribute__((address_space(3))) void*)lp,
                                     16, 0, 0);
  }
}

// acc += A(128x128 swizzled LDS) @ W(128x128 swizzled LDS)^T ; wave tile 64x32
__device__ __forceinline__ void gemmS(const u16* A, const u16* W,
                                      f32x4 (&acc)[4][2], int wr, int wc, int l16, int l4) {
#pragma unroll
  for (int ks = 0; ks < 4; ++ks) {
    int gsl = ks * 4 + l4;
    bf16x8 av[4], bv[2];
#pragma unroll
    for (int nr = 0; nr < 2; ++nr) {
      int rW = wc * 32 + nr * 16 + l16;
      bv[nr] = *(const bf16x8*)&W[rW * 128 + ((gsl ^ (rW & 7)) << 3)];
    }
#pragma unroll
    for (int mr = 0; mr < 4; ++mr) {
      int rA = wr * 64 + mr * 16 + l16;
      av[mr] = *(const bf16x8*)&A[rA * 128 + ((gsl ^ (rA & 7)) << 3)];
    }
#pragma unroll
    for (int mr = 0; mr < 4; ++mr)
#pragma unroll
      for (int nr = 0; nr < 2; ++nr)
        acc[mr][nr] = __builtin_amdgcn_mfma_f32_16x16x32_bf16(av[mr], bv[nr], acc[mr][nr], 0, 0, 0);
  }
}

extern "C" __global__ __launch_bounds__(NTHR, 2) void fused_flow(
    const int* __restrict__ seen_edges, const int* __restrict__ memorized,
    const float* __restrict__ node_att,
    const float* __restrict__ msg_b1, const float* __restrict__ msg_b2,
    const float* __restrict__ hid_b1, const float* __restrict__ hid_b2,
    float* __restrict__ out) {
  __shared__ u16 sA0[16384], sA1[16384];   // A-tile double buffer (swizzled)
  __shared__ u16 sW0b[16384], sW2b[16384]; // W tiles (swizzled)
  __shared__ int sEg[4][BM], sRel[4][BM], sVi[4][BM];
  __shared__ int sMeg[BM], sMvm[BM];
  __shared__ float sNA[BM];

  const int tid = threadIdx.x;
  const int lane = tid & 63, wid = tid >> 6;
  const int wr = wid >> 2, wc = wid & 3;   // 2x4 wave grid, 64x32 per wave
  const int l16 = lane & 15, l4 = lane >> 4;
  const int j0 = blockIdx.x * BM;

  float mb1v[2], mb2v[2], hb1v[2], hb2v[2];
#pragma unroll
  for (int nr = 0; nr < 2; ++nr) {
    int col = wc * 32 + nr * 16 + l16;
    mb1v[nr] = msg_b1[col]; mb2v[nr] = msg_b2[col];
    hb1v[nr] = hid_b1[col]; hb2v[nr] = hid_b2[col];
  }

  // ---- prologue: W0<-vi-tile, W2<-vj-tile, sA0<-vj rows; index staging ----
  gload_lin(sW0b, g_WT + TIL(0), wid, lane);
  gload_lin(sW2b, g_WT + TIL(1), wid, lane);
  gload_rows(sA0, g_hb, nullptr, j0, wid, lane);
  {
    int t = tid >> 7, r = tid & 127;
    int e = j0 + r + t * N_MEM_C;
    const int4* se = (const int4*)seen_edges + (size_t)e * 2;
    int4 lo = se[0], hi = se[1];
    sEg[t][r] = min(max(lo.x, 0), 63);
    sRel[t][r] = min(max(lo.w, 0), 499);
    sVi[t][r] = min(max(hi.z, 0), N_MEM_C - 1);
  }
  if (tid < BM) {
    int2 mn = ((const int2*)memorized)[j0 + tid];
    int eg = min(max(mn.x, 0), 63);
    int vm = min(max(mn.y, 0), NNODES_C - 1);
    sMeg[tid] = eg; sMvm[tid] = vm;
    sNA[tid] = node_att[(size_t)eg * NNODES_C + vm];
  }
  WAIT_LG0(); SBAR();                       // indices visible
  gload_rows(sA1, g_hb, sVi[0], 0, wid, lane);   // A(0)
  WAIT_VM0(); SBAR();                       // W0, Wvj, vj-tile, A(0) resident

  const f32x4 zero4 = {0.f, 0.f, 0.f, 0.f};
  f32x4 acc_vj[4][2], aggr[4][2];
#pragma unroll
  for (int a = 0; a < 4; ++a)
#pragma unroll
    for (int b = 0; b < 2; ++b) { acc_vj[a][b] = zero4; aggr[a][b] = zero4; }
  gemmS(sA0, sW2b, acc_vj, wr, wc, l16, l4);     // vj chunk (shared by all tiles)
  SBAR();                                   // sA0 / sW2b free
  gload_lin(sW2b, g_WT + TIL(2), wid, lane);     // msg_W2
  gload_rows(sA0, g_hb, sVi[1], 0, wid, lane);   // A(1)

  // ---- edge loop; A(t) in (t even ? sA1 : sA0) ----
#pragma unroll 1
  for (int t = 0; t < 4; ++t) {
    u16* Acur = (t & 1) ? sA0 : sA1;
    f32x4 acc[4][2];
#pragma unroll
    for (int a = 0; a < 4; ++a)
#pragma unroll
      for (int b = 0; b < 2; ++b) acc[a][b] = acc_vj[a][b];
    gemmS(Acur, sW0b, acc, wr, wc, l16, l4);     // vi chunk

    // gather-add: rel + query contributions (f32 tables, L2-hot)
#pragma unroll
    for (int mr = 0; mr < 4; ++mr)
#pragma unroll
      for (int i = 0; i < 4; ++i) {
        int r = wr * 64 + mr * 16 + l4 * 4 + i;
        const float* pr = g_relW + sRel[t][r] * 128;
        const float* pq = g_qsumM + sEg[t][r] * 128;
#pragma unroll
        for (int nr = 0; nr < 2; ++nr) {
          int c = wc * 32 + nr * 16 + l16;
          acc[mr][nr][i] += pr[c] + pq[c];
        }
      }
    SBAR();                                 // B1: all waves done reading A(t)

    // h = leaky_relu(acc + b1) -> Acur (swizzled)
#pragma unroll
    for (int mr = 0; mr < 4; ++mr)
#pragma unroll
      for (int nr = 0; nr < 2; ++nr)
#pragma unroll
        for (int i = 0; i < 4; ++i) {
          float v = acc[mr][nr][i] + mb1v[nr];
          v = (v >= 0.f) ? v : 0.2f * v;
          int r = wr * 64 + mr * 16 + l4 * 4 + i;
          Acur[swz_off(r, wc * 32 + nr * 16 + l16)] = f2bf_s(v);
        }
    WAIT_LG0();
    if (t == 0) { WAIT_VM4(); }             // drain msg_W2 (oldest), keep A(1)
    SBAR();                                 // B2: h visible (+W2 at t=0)

    f32x4 acc2[4][2];
#pragma unroll
    for (int a = 0; a < 4; ++a)
#pragma unroll
      for (int b = 0; b < 2; ++b) acc2[a][b] = zero4;
    gemmS(Acur, sW2b, acc2, wr, wc, l16, l4);    // h @ msg_W2
#pragma unroll
    for (int mr = 0; mr < 4; ++mr)
#pragma unroll
      for (int nr = 0; nr < 2; ++nr)
#pragma unroll
        for (int i = 0; i < 4; ++i)
          aggr[mr][nr][i] += fast_tanh(acc2[mr][nr][i] + mb2v[nr]);
    WAIT_VM0();                             // A(t+1) LDS writes complete
    SBAR();                                 // B3: visible to all waves; Acur free
    if (t < 2)
      gload_rows(Acur, g_hb, sVi[t + 2], 0, wid, lane);   // A(t+2) -> Acur
  }

  // ---- update phase. sA0 = h(3) dead, sA1 = h(2) dead ----
  gload_lin(sW0b, g_WT + TIL(3), wid, lane);     // hid_W1 aggr chunk
  gload_lin(sW2b, g_WT + TIL(4), wid, lane);     // hid_W1 hidden chunk
  gload_rows(sA0, g_hb, nullptr, j0, wid, lane); // hidden[m] rows
  // aggr tile (0.5 * aggr) -> sA1 (swizzled)
#pragma unroll
  for (int mr = 0; mr < 4; ++mr)
#pragma unroll
    for (int nr = 0; nr < 2; ++nr)
#pragma unroll
      for (int i = 0; i < 4; ++i) {
        int r = wr * 64 + mr * 16 + l4 * 4 + i;
        sA1[swz_off(r, wc * 32 + nr * 16 + l16)] = f2bf_s(0.5f * aggr[mr][nr][i]);
      }
  WAIT_LG0(); WAIT_VM0(); SBAR();

  f32x4 accU[4][2];
#pragma unroll
  for (int a = 0; a < 4; ++a)
#pragma unroll
    for (int b = 0; b < 2; ++b) accU[a][b] = zero4;
  gemmS(sA1, sW0b, accU, wr, wc, l16, l4);       // aggr chunk
  SBAR();                                   // sW0b, sA1 free
  gload_lin(sW0b, g_WT + TIL(5), wid, lane);     // Weff
  gload_rows(sA1, g_ub, sMvm, 0, wid, lane);     // uncon rows (unscaled)
  gemmS(sA0, sW2b, accU, wr, wc, l16, l4);       // hidden chunk
  SBAR();                                   // sW2b free
  gload_lin(sW2b, g_WT + TIL(6), wid, lane);     // hid_W2
  WAIT_VM4(); SBAR();                       // Weff + uncon resident; W2 in flight

  f32x4 acc2[4][2];
#pragma unroll
  for (int a = 0; a < 4; ++a)
#pragma unroll
    for (int b = 0; b < 2; ++b) acc2[a][b] = zero4;
  gemmS(sA1, sW0b, acc2, wr, wc, l16, l4);       // uncon @ Weff (unscaled rows)
#pragma unroll
  for (int mr = 0; mr < 4; ++mr)
#pragma unroll
    for (int i = 0; i < 4; ++i) {
      int r = wr * 64 + mr * 16 + l4 * 4 + i;
      float na = sNA[r];
      const float* pq = g_qsumH + sMeg[r] * 128;
#pragma unroll
      for (int nr = 0; nr < 2; ++nr)
        accU[mr][nr][i] += na * acc2[mr][nr][i] + pq[wc * 32 + nr * 16 + l16];
    }
  // h -> sA0 (its readers finished before previous barriers)
#pragma unroll
  for (int mr = 0; mr < 4; ++mr)
#pragma unroll
    for (int nr = 0; nr < 2; ++nr)
#pragma unroll
      for (int i = 0; i < 4; ++i) {
        float v = accU[mr][nr][i] + hb1v[nr];
        v = (v >= 0.f) ? v : 0.2f * v;
        int r = wr * 64 + mr * 16 + l4 * 4 + i;
        sA0[swz_off(r, wc * 32 + nr * 16 + l16)] = f2bf_s(v);
      }
  WAIT_LG0(); WAIT_VM0(); SBAR();           // h visible, hid_W2 resident

  f32x4 accF[4][2];
#pragma unroll
  for (int a = 0; a < 4; ++a)
#pragma unroll
    for (int b = 0; b < 2; ++b) accF[a][b] = zero4;
  gemmS(sA0, sW2b, accF, wr, wc, l16, l4);

#pragma unroll
  for (int mr = 0; mr < 4; ++mr)
#pragma unroll
    for (int nr = 0; nr < 2; ++nr)
#pragma unroll
      for (int i = 0; i < 4; ++i) {
        int row = j0 + wr * 64 + mr * 16 + l4 * 4 + i;
        int col = wc * 32 + nr * 16 + l16;
        size_t o = (size_t)row * DDIM + col;
        out[o] = bf2f(g_hb[o]) + fast_tanh(accF[mr][nr][i] + hb2v[nr]);
      }
}

extern "C" void kernel_launch(void* const* d_in, const int* in_sizes, int n_in,
                              void* d_out, int out_size, void* d_ws, size_t ws_size,
                              hipStream_t stream) {
  (void)in_sizes; (void)n_in; (void)out_size; (void)d_ws; (void)ws_size;
  const float* hidden       = (const float*)d_in[0];
  const int*   seen_edges   = (const int*)d_in[1];
  const int*   memorized    = (const int*)d_in[2];
  const float* node_att     = (const float*)d_in[3];
  const float* hidden_uncon = (const float*)d_in[4];
  const float* qh           = (const float*)d_in[5];
  const float* qr           = (const float*)d_in[6];
  const float* rel_table    = (const float*)d_in[7];
  const float* msg_W1       = (const float*)d_in[8];
  const float* msg_b1       = (const float*)d_in[9];
  const float* msg_W2       = (const float*)d_in[10];
  const float* msg_b2       = (const float*)d_in[11];
  const float* hid_W1       = (const float*)d_in[12];
  const float* hid_b1       = (const float*)d_in[13];
  const float* hid_W2       = (const float*)d_in[14];
  const float* hid_b2       = (const float*)d_in[15];
  const float* int_W        = (const float*)d_in[16];

  prep_conv<<<dim3(7221), dim3(256), 0, stream>>>(hidden, hidden_uncon);
  prep_wt<<<dim3(6 * 16384 / 256), dim3(256), 0, stream>>>(msg_W1, msg_W2, hid_W1, hid_W2);
  prep_weff<<<dim3(64), dim3(256), 0, stream>>>(hid_W1, int_W);
  prep_relW<<<dim3(250), dim3(256), 0, stream>>>(rel_table, msg_W1);
  prep_qsum<<<dim3(32), dim3(256), 0, stream>>>(qh, qr, msg_W1, hid_W1);
  fused_flow<<<dim3(N_MEM_C / BM), dim3(NTHR), 0, stream>>>(
      seen_edges, memorized, node_att, msg_b1, msg_b2, hid_b1, hid_b2, (float*)d_out);
}